// Round 3
// baseline (440.483 us; speedup 1.0000x reference)
//
#include <hip/hip_runtime.h>

#define HID 512
#define OD  256
#define HP  513
#define KD  263169          /* 513*513 */
#define MT  128             /* stage1 rows per block */
#define NB  1026            /* 131328 / MT */
#define KP  576             /* padded K (9*64) */
#define NS  9
#define EPSV 1e-5f

typedef float f32x4 __attribute__((ext_vector_type(4)));
typedef short s16x8 __attribute__((ext_vector_type(8)));

static __device__ __forceinline__ unsigned short f2bf(float f) {
    union { float f; unsigned u; } x; x.f = f;
    unsigned r = x.u + 0x7FFFu + ((x.u >> 16) & 1u);   // RNE
    return (unsigned short)(r >> 16);
}

// ---------- prep: gb interleave, vhT (bf16, 128 rows, padded), ahT ----------
__global__ void prep_all(const float* __restrict__ a, const float* __restrict__ v,
                         const float* __restrict__ gamma, const float* __restrict__ beta,
                         float* __restrict__ gb, unsigned short* __restrict__ vhT,
                         float* __restrict__ ahT) {
    int b = blockIdx.x, t = threadIdx.x;
    if (b < 1029) {
        int d = b * 256 + t;
        if (d < KD) {
            float2 g; g.x = gamma[d]; g.y = beta[d];
            *(float2*)(gb + 2 * (size_t)d) = g;
        }
    } else if (b < 1029 + 128) {
        int n = b - 1029;
        for (int j = t; j < KP; j += 256) {
            float val = 0.f;
            if (j == 0) val = 1.f;
            else if (j <= 512) val = v[n * HID + j - 1];
            vhT[n * KP + j] = f2bf(val);
        }
    } else {
        int idx = (b - 1029 - 128) * 256 + t;
        if (idx < HP * 128) {
            int i = idx >> 7, m = idx & 127;
            ahT[idx] = (i == 0) ? 1.f : a[m * HID + i - 1];
        }
    }
}

// ---------- stats ------------------------------------------------------------
__global__ void stats_kernel(const float* __restrict__ a, const float* __restrict__ v,
                             float* __restrict__ mu, float* __restrict__ rsig) {
    __shared__ float s1[256], s2[256], s3[256], s4[256];
    int m = blockIdx.x, t = threadIdx.x;
    float a0 = a[m * HID + t], a1 = a[m * HID + t + 256];
    float v0 = v[m * HID + t], v1 = v[m * HID + t + 256];
    s1[t] = a0 + a1; s2[t] = a0 * a0 + a1 * a1;
    s3[t] = v0 + v1; s4[t] = v0 * v0 + v1 * v1;
    __syncthreads();
    for (int off = 128; off > 0; off >>= 1) {
        if (t < off) { s1[t] += s1[t + off]; s2[t] += s2[t + off];
                       s3[t] += s3[t + off]; s4[t] += s4[t + off]; }
        __syncthreads();
    }
    if (t == 0) {
        float Sa = 1.f + s1[0], Qa = 1.f + s2[0];
        float Sv = 1.f + s3[0], Qv = 1.f + s4[0];
        float muv = Sa * Sv / (float)KD;
        float var = Qa * Qv / (float)KD - muv * muv;
        mu[m]   = muv;
        rsig[m] = rsqrtf(var + EPSV);
    }
}

// ---------- stage1 -----------------------------------------------------------
// A row oi = gamma*W[oi-slice]; B = vhT (bf16). acc = T[oi][m]; epilogue folds
// ah-weighted reduction -> Pblk; Sg/Sb accumulated in f32 during staging.
__global__ __launch_bounds__(512, 4) void stage1(
        const float* __restrict__ W, const float* __restrict__ gb,
        const unsigned short* __restrict__ vhT, const float* __restrict__ ahT,
        float* __restrict__ Pblk, float* __restrict__ SgPart, float* __restrict__ SbPart) {
    __shared__ __align__(16) char arena[34816];
    unsigned short* Bs = (unsigned short*)(arena + 16384);   // [128][72]
    float* red = (float*)arena;                              // epilogue [2][8][16][8]
    float* sgw = (float*)(arena + 8192);                     // [2][8]
    float* sbw = (float*)(arena + 8256);                     // [2][8]

    const int tid  = threadIdx.x;
    const int lane = tid & 63, w = tid >> 6;
    const int lr = lane & 15, lg = lane >> 4;
    const int b = blockIdx.x;
    const unsigned oi0    = (unsigned)b * (unsigned)MT;
    const unsigned ofirst = oi0 / (unsigned)HP;
    const unsigned osw    = (ofirst + 1u) * (unsigned)HP;

    const int r0 = tid >> 6;     // staging row base (0..7), rows r0+8i
    const int kl = tid & 63;     // staging k lane
    const unsigned dbase = ((oi0 + (unsigned)r0) * (unsigned)HP) % (unsigned)KD;

    float  wv[16];
    float2 g2[16];
    uint4  bv[2];
    float sg0 = 0.f, sg1 = 0.f, sb0 = 0.f, sb1 = 0.f;

    f32x4 acc[8];
#pragma unroll
    for (int nt = 0; nt < 8; ++nt) acc[nt] = {0.f, 0.f, 0.f, 0.f};

    // ---- issue loads for step s (W + gb -> regs, vhT -> regs)
    auto ISSUE = [&](int s) {
        const int j = s * 64 + kl;
        const bool jv = (j < HP);
        unsigned d = dbase + (unsigned)j; if (d >= (unsigned)KD) d -= (unsigned)KD;
        const float* wp = W + (size_t)(oi0 + (unsigned)r0) * HP + j;
#pragma unroll
        for (int i = 0; i < 16; ++i) {
            if (jv) {
                wv[i] = *wp;
                g2[i] = *(const float2*)(gb + 2 * (size_t)d);
            } else {
                wv[i] = 0.f; g2[i].x = 0.f; g2[i].y = 0.f;
            }
            wp += 8 * HP;
            d += 8u * (unsigned)HP; if (d >= (unsigned)KD) d -= (unsigned)KD;
        }
#pragma unroll
        for (int c = 0; c < 2; ++c) {
            int idx = tid + c * 512;
            int n = idx >> 3, kk = (idx & 7) * 8;
            bv[c] = *(const uint4*)&vhT[n * KP + s * 64 + kk];
        }
    };

    ISSUE(0);
    for (int s = 0; s < NS; ++s) {
        __syncthreads();   // previous MFMA done reading LDS
        // ---- convert + write A (swizzled), accumulate Sg/Sb
#pragma unroll
        for (int i = 0; i < 16; ++i) {
            const int r = r0 + 8 * i;
            float p = g2[i].x * wv[i];
            float q = g2[i].y * wv[i];
            if (oi0 + (unsigned)r >= osw) { sg1 += p; sb1 += q; }
            else                          { sg0 += p; sb0 += q; }
            unsigned byte = (unsigned)(r * 128 + kl * 2) ^ (unsigned)((r & 7) << 4);
            *(unsigned short*)(arena + byte) = f2bf(p);
        }
#pragma unroll
        for (int c = 0; c < 2; ++c) {
            int idx = tid + c * 512;
            int n = idx >> 3, kk = (idx & 7) * 8;
            *(uint4*)&Bs[n * 72 + kk] = bv[c];
        }
        __syncthreads();
        if (s + 1 < NS) ISSUE(s + 1);   // loads fly under MFMA
        // ---- MFMA: wave owns rows w*16..+16 (1 A-frag, 8 B-frags per ks)
#pragma unroll
        for (int ks = 0; ks < 2; ++ks) {
            s16x8 bfr[8];
#pragma unroll
            for (int nt = 0; nt < 8; ++nt)
                bfr[nt] = *(const s16x8*)&Bs[(nt * 16 + lr) * 72 + ks * 32 + lg * 8];
            const unsigned row = (unsigned)(w * 16 + lr);
            const unsigned off = (row * 128u + (unsigned)(ks * 64 + lg * 16)) ^ ((row & 7u) << 4);
            s16x8 afr = *(const s16x8*)(arena + off);
#pragma unroll
            for (int nt = 0; nt < 8; ++nt)
                acc[nt] = __builtin_amdgcn_mfma_f32_16x16x32_bf16(afr, bfr[nt], acc[nt], 0, 0, 0);
        }
    }
    __syncthreads();   // done with As/Bs; arena reused for reduction

    // ---- epilogue: P[m] += ah[m,i] * T[oi][m], slot-split by o --------------
    float psum[2][8];
#pragma unroll
    for (int sl = 0; sl < 2; ++sl)
#pragma unroll
        for (int nt = 0; nt < 8; ++nt) psum[sl][nt] = 0.f;

    const unsigned oib = oi0 + (unsigned)(w * 16 + lg * 4);
#pragma unroll
    for (int e = 0; e < 4; ++e) {
        unsigned oi = oib + (unsigned)e;
        int sl = (oi >= osw) ? 1 : 0;
        unsigned i = oi - (sl ? osw : ofirst * (unsigned)HP);
        const float* ahr = ahT + (size_t)i * 128;
#pragma unroll
        for (int nt = 0; nt < 8; ++nt)
            psum[sl][nt] = fmaf(acc[nt][e], ahr[nt * 16 + lr], psum[sl][nt]);
    }
#pragma unroll
    for (int sl = 0; sl < 2; ++sl)
#pragma unroll
        for (int nt = 0; nt < 8; ++nt) {
            float r = psum[sl][nt];
            r += __shfl_xor(r, 16);
            r += __shfl_xor(r, 32);
            psum[sl][nt] = r;
        }
    if (lane < 16) {
#pragma unroll
        for (int sl = 0; sl < 2; ++sl)
#pragma unroll
            for (int nt = 0; nt < 8; ++nt)
                red[(size_t)((sl * 128 + nt * 16 + lr) * 8 + w)] = psum[sl][nt];
    }
    // Sg/Sb wave reduce
    float t0 = sg0, t1 = sg1, u0 = sb0, u1 = sb1;
#pragma unroll
    for (int off = 1; off < 64; off <<= 1) {
        t0 += __shfl_xor(t0, off); t1 += __shfl_xor(t1, off);
        u0 += __shfl_xor(u0, off); u1 += __shfl_xor(u1, off);
    }
    if (lane == 0) { sgw[w] = t0; sgw[8 + w] = t1; sbw[w] = u0; sbw[8 + w] = u1; }
    __syncthreads();

    for (int idx = tid; idx < 256; idx += 512) {
        const float* rp = red + (size_t)idx * 8;
        float val = rp[0] + rp[1] + rp[2] + rp[3] + rp[4] + rp[5] + rp[6] + rp[7];
        int sl = idx >> 7, c = idx & 127;
        Pblk[((size_t)b * 2 + sl) * 128 + c] = val;
    }
    if (tid < 2) {
        float S = 0.f, T = 0.f;
#pragma unroll
        for (int k = 0; k < 8; ++k) { S += sgw[tid * 8 + k]; T += sbw[tid * 8 + k]; }
        SgPart[b * 2 + tid] = S;
        SbPart[b * 2 + tid] = T;
    }
}

// ---------- finalize ---------------------------------------------------------
__global__ void finalize_kernel(const float* __restrict__ Pblk, const float* __restrict__ SgPart,
                                const float* __restrict__ SbPart, const float* __restrict__ mu,
                                const float* __restrict__ rsig, const float* __restrict__ bias,
                                float* __restrict__ out) {
    int o = blockIdx.x, m = threadIdx.x;   // 128 threads
    __shared__ float sSg, sSb;
    int b0 = (o * HP) >> 7;
    int b1 = (o * HP + HP - 1) >> 7;
    float P = 0.f, Sg = 0.f, Sb = 0.f;
    for (int b = b0; b <= b1; ++b) {
        unsigned of = ((unsigned)b * (unsigned)MT) / (unsigned)HP;
        int sl = o - (int)of;
        if (sl < 0 || sl > 1) continue;
        P += Pblk[((size_t)b * 2 + sl) * 128 + m];
        if (m == 0) { Sg += SgPart[b * 2 + sl]; Sb += SbPart[b * 2 + sl]; }
    }
    if (m == 0) { sSg = Sg; sSb = Sb; }
    __syncthreads();
    float x = rsig[m] * (P - mu[m] * sSg) + sSb + bias[o];
    out[m * OD + o] = fmaxf(x, 0.f);
}

extern "C" void kernel_launch(void* const* d_in, const int* in_sizes, int n_in,
                              void* d_out, int out_size, void* d_ws, size_t ws_size,
                              hipStream_t stream) {
    const float* a     = (const float*)d_in[0];
    const float* v     = (const float*)d_in[1];
    const float* gamma = (const float*)d_in[2];
    const float* beta  = (const float*)d_in[3];
    const float* W     = (const float*)d_in[4];
    const float* bias  = (const float*)d_in[5];
    float* out = (float*)d_out;

    float* cur = (float*)d_ws;
    float* mu     = cur; cur += 128;
    float* rsig   = cur; cur += 128;
    float* SbPart = cur; cur += NB * 2;            // 2052
    float* SgPart = cur; cur += NB * 2;            // 2052
    float* Pblk   = cur; cur += (size_t)NB * 2 * 128;
    float* ahT    = cur; cur += (size_t)HP * 128;
    float* gb     = cur; cur += (size_t)2 * KD + 2;  // pad to keep 16B alignment
    unsigned short* vhT = (unsigned short*)cur;      // 128*KP ushorts

    prep_all<<<1029 + 128 + 257, 256, 0, stream>>>(a, v, gamma, beta, gb, vhT, ahT);
    stats_kernel<<<128, 256, 0, stream>>>(a, v, mu, rsig);
    stage1<<<NB, 512, 0, stream>>>(W, gb, vhT, ahT, Pblk, SgPart, SbPart);
    finalize_kernel<<<OD, 128, 0, stream>>>(Pblk, SgPart, SbPart, mu, rsig, bias, out);
}

// Round 4
// 242.561 us; speedup vs baseline: 1.8160x; 1.8160x over previous
//
#include <hip/hip_runtime.h>

#define HID 512
#define OD  256
#define HP  513
#define GPS 516              /* padded gamma/beta row stride (floats, 16B-aligned) */
#define NB  1026             /* 131328 / 128 rows per block */
#define EPSV 1e-5f

typedef float f32x4 __attribute__((ext_vector_type(4)));
typedef short s16x8 __attribute__((ext_vector_type(8)));

static __device__ __forceinline__ unsigned short f2bf(float f) {
    union { float f; unsigned u; } x; x.f = f;
    unsigned r = x.u + 0x7FFFu + ((x.u >> 16) & 1u);   // RNE
    return (unsigned short)(r >> 16);
}

// ---------- prep: padded gamma/beta, vhT bf16 [128][512], vh512, ahT --------
__global__ void prep_all(const float* __restrict__ a, const float* __restrict__ v,
                         const float* __restrict__ gamma, const float* __restrict__ beta,
                         float* __restrict__ gp, float* __restrict__ bp,
                         unsigned short* __restrict__ vhT, float* __restrict__ vh512,
                         float* __restrict__ ahT) {
    int b = blockIdx.x, t = threadIdx.x;
    if (b < HP) {
        int i = b;
        for (int j = t; j < GPS; j += 256) {
            float g = 0.f, bb = 0.f;
            if (j < HP) { g = gamma[(size_t)i * HP + j]; bb = beta[(size_t)i * HP + j]; }
            gp[(size_t)i * GPS + j] = g;
            bp[(size_t)i * GPS + j] = bb;
        }
    } else if (b < HP + 128) {
        int m = b - HP;
        for (int k = t; k < 512; k += 256) {
            float val = (k == 0) ? 1.f : v[m * HID + k - 1];
            vhT[m * 512 + k] = f2bf(val);
        }
    } else if (b == HP + 128) {
        if (t < 128) vh512[t] = v[t * HID + 511];
    } else {
        int idx = (b - HP - 129) * 256 + t;
        if (idx < HP * 128) {
            int i = idx >> 7, m = idx & 127;
            ahT[idx] = (i == 0) ? 1.f : a[m * HID + i - 1];
        }
    }
}

// ---------- stats ------------------------------------------------------------
__global__ void stats_kernel(const float* __restrict__ a, const float* __restrict__ v,
                             float* __restrict__ mu, float* __restrict__ rsig) {
    __shared__ float s1[256], s2[256], s3[256], s4[256];
    int m = blockIdx.x, t = threadIdx.x;
    float a0 = a[m * HID + t], a1 = a[m * HID + t + 256];
    float v0 = v[m * HID + t], v1 = v[m * HID + t + 256];
    s1[t] = a0 + a1; s2[t] = a0 * a0 + a1 * a1;
    s3[t] = v0 + v1; s4[t] = v0 * v0 + v1 * v1;
    __syncthreads();
    for (int off = 128; off > 0; off >>= 1) {
        if (t < off) { s1[t] += s1[t + off]; s2[t] += s2[t + off];
                       s3[t] += s3[t + off]; s4[t] += s4[t + off]; }
        __syncthreads();
    }
    if (t == 0) {
        float Sa = 1.f + s1[0], Qa = 1.f + s2[0];
        float Sv = 1.f + s3[0], Qv = 1.f + s4[0];
        float muv = Sa * Sv / (float)(HP * HP);
        float var = Qa * Qv / (float)(HP * HP) - muv * muv;
        mu[m]   = muv;
        rsig[m] = rsqrtf(var + EPSV);
    }
}

// ---------- stage1: barrier-free streaming MFMA GEMM -------------------------
// Lane owns A row oi0+w*16+lr, k=lg*8..+8; loads W/gamma/beta direct from
// global, B-frags direct from vhT. K = 16 dense steps of 32 (j<512), j=512
// peeled into epilogue. No LDS, no barriers in main loop.
__global__ __launch_bounds__(512, 4) void stage1(
        const float* __restrict__ W, const float* __restrict__ gp,
        const float* __restrict__ bp, const unsigned short* __restrict__ vhT,
        const float* __restrict__ vh512, const float* __restrict__ ahT,
        float* __restrict__ Pblk, float* __restrict__ SgPart, float* __restrict__ SbPart) {
    __shared__ float red0[128][8];
    __shared__ float red1[128][8];
    __shared__ float sgr[2][8], sbr[2][8];

    const int tid = threadIdx.x, lane = tid & 63, w = tid >> 6;
    const int lr = lane & 15, lg = lane >> 4;
    const int b = blockIdx.x;
    const unsigned oi0 = (unsigned)b * 128u;
    const unsigned ofirst = oi0 / 513u;
    const unsigned osw = (ofirst + 1u) * 513u;

    const unsigned row = oi0 + (unsigned)(w * 16 + lr);
    const unsigned irow = row - ((row >= osw) ? osw : ofirst * 513u);

    const float* Wp = W + (size_t)row * 513u + (unsigned)(lg * 8);
    const float* Gp = gp + (size_t)irow * GPS + (unsigned)(lg * 8);
    const float* Bp = bp + (size_t)irow * GPS + (unsigned)(lg * 8);
    const unsigned short* Vp = vhT + lr * 512 + lg * 8;

    f32x4 acc[8];
#pragma unroll
    for (int nt = 0; nt < 8; ++nt) acc[nt] = {0.f, 0.f, 0.f, 0.f};
    float sg = 0.f, sb = 0.f;

#pragma unroll 2
    for (int s = 0; s < 16; ++s) {
        const int ko = s * 32;
        float wv[8];
        __builtin_memcpy(wv, Wp + ko, 32);   // 4B-aligned W row; compiler merges as legal
        f32x4 g0 = *(const f32x4*)(Gp + ko);
        f32x4 g1 = *(const f32x4*)(Gp + ko + 4);
        f32x4 h0 = *(const f32x4*)(Bp + ko);
        f32x4 h1 = *(const f32x4*)(Bp + ko + 4);
        s16x8 afr;
#pragma unroll
        for (int e = 0; e < 4; ++e) {
            float p0 = g0[e] * wv[e];
            float p1 = g1[e] * wv[4 + e];
            sg += p0 + p1;
            sb = fmaf(h0[e], wv[e], sb);
            sb = fmaf(h1[e], wv[4 + e], sb);
            afr[e]     = (short)f2bf(p0);
            afr[4 + e] = (short)f2bf(p1);
        }
#pragma unroll
        for (int nt = 0; nt < 8; ++nt) {
            s16x8 bfr = *(const s16x8*)(Vp + nt * (16 * 512) + ko);
            acc[nt] = __builtin_amdgcn_mfma_f32_16x16x32_bf16(afr, bfr, acc[nt], 0, 0, 0);
        }
    }

    // ---- peel j=512 (rank-1 term), accumulate into acc + Sg/Sb --------------
    const unsigned oib = oi0 + (unsigned)(w * 16 + lg * 4);
    float c512[4];
    float psg0 = 0.f, psg1 = 0.f, psb0 = 0.f, psb1 = 0.f;
#pragma unroll
    for (int e = 0; e < 4; ++e) {
        unsigned oi = oib + (unsigned)e;
        bool hi = (oi >= osw);
        unsigned ii = oi - (hi ? osw : ofirst * 513u);
        float wv = W[(size_t)oi * 513u + 512u];
        float g  = gp[(size_t)ii * GPS + 512];
        float h  = bp[(size_t)ii * GPS + 512];
        float p = g * wv, q = h * wv;
        c512[e] = p;
        if (lr == 0) {   // one lane per (lg) row-group contributes the sums
            psg0 += hi ? 0.f : p; psg1 += hi ? p : 0.f;
            psb0 += hi ? 0.f : q; psb1 += hi ? q : 0.f;
        }
    }
#pragma unroll
    for (int nt = 0; nt < 8; ++nt) {
        float vm = vh512[nt * 16 + lr];
#pragma unroll
        for (int e = 0; e < 4; ++e)
            acc[nt][e] = fmaf(c512[e], vm, acc[nt][e]);
    }
    {   // main-loop Sg/Sb into slot accumulators (slot uniform per lane)
        bool hi = (row >= osw);
        psg0 += hi ? 0.f : sg; psg1 += hi ? sg : 0.f;
        psb0 += hi ? 0.f : sb; psb1 += hi ? sb : 0.f;
    }

    // ---- epilogue: ah-weighted fold, slot-split (static arrays, predicated) -
    float p0[8], p1[8];
#pragma unroll
    for (int nt = 0; nt < 8; ++nt) { p0[nt] = 0.f; p1[nt] = 0.f; }
#pragma unroll
    for (int e = 0; e < 4; ++e) {
        unsigned oi = oib + (unsigned)e;
        bool hi = (oi >= osw);
        unsigned ii = oi - (hi ? osw : ofirst * 513u);
        const float* ahr = ahT + (size_t)ii * 128;
#pragma unroll
        for (int nt = 0; nt < 8; ++nt) {
            float val = acc[nt][e] * ahr[nt * 16 + lr];
            p0[nt] += hi ? 0.f : val;
            p1[nt] += hi ? val : 0.f;
        }
    }
#pragma unroll
    for (int nt = 0; nt < 8; ++nt) {
        float r0 = p0[nt], r1 = p1[nt];
        r0 += __shfl_xor(r0, 16); r0 += __shfl_xor(r0, 32);
        r1 += __shfl_xor(r1, 16); r1 += __shfl_xor(r1, 32);
        p0[nt] = r0; p1[nt] = r1;
    }
    if (lane < 16) {
#pragma unroll
        for (int nt = 0; nt < 8; ++nt) {
            red0[nt * 16 + lr][w] = p0[nt];
            red1[nt * 16 + lr][w] = p1[nt];
        }
    }
#pragma unroll
    for (int off = 1; off < 64; off <<= 1) {
        psg0 += __shfl_xor(psg0, off); psg1 += __shfl_xor(psg1, off);
        psb0 += __shfl_xor(psb0, off); psb1 += __shfl_xor(psb1, off);
    }
    if (lane == 0) { sgr[0][w] = psg0; sgr[1][w] = psg1; sbr[0][w] = psb0; sbr[1][w] = psb1; }
    __syncthreads();
    if (tid < 256) {
        int sl = tid >> 7, m = tid & 127;
        const float* rp = sl ? &red1[m][0] : &red0[m][0];
        float s = rp[0] + rp[1] + rp[2] + rp[3] + rp[4] + rp[5] + rp[6] + rp[7];
        Pblk[((size_t)b * 2 + sl) * 128 + m] = s;
    }
    if (tid < 2) {
        float S = 0.f, T = 0.f;
#pragma unroll
        for (int k2 = 0; k2 < 8; ++k2) { S += sgr[tid][k2]; T += sbr[tid][k2]; }
        SgPart[b * 2 + tid] = S;
        SbPart[b * 2 + tid] = T;
    }
}

// ---------- finalize ---------------------------------------------------------
__global__ void finalize_kernel(const float* __restrict__ Pblk, const float* __restrict__ SgPart,
                                const float* __restrict__ SbPart, const float* __restrict__ mu,
                                const float* __restrict__ rsig, const float* __restrict__ bias,
                                float* __restrict__ out) {
    int o = blockIdx.x, m = threadIdx.x;   // 128 threads
    __shared__ float sSg, sSb;
    int b0 = (o * HP) >> 7;
    int b1 = (o * HP + HP - 1) >> 7;
    float P = 0.f, Sg = 0.f, Sb = 0.f;
    for (int b = b0; b <= b1; ++b) {
        unsigned of = ((unsigned)b * 128u) / 513u;
        int sl = o - (int)of;
        if (sl < 0 || sl > 1) continue;
        P += Pblk[((size_t)b * 2 + sl) * 128 + m];
        if (m == 0) { Sg += SgPart[b * 2 + sl]; Sb += SbPart[b * 2 + sl]; }
    }
    if (m == 0) { sSg = Sg; sSb = Sb; }
    __syncthreads();
    float x = rsig[m] * (P - mu[m] * sSg) + sSb + bias[o];
    out[m * OD + o] = fmaxf(x, 0.f);
}

extern "C" void kernel_launch(void* const* d_in, const int* in_sizes, int n_in,
                              void* d_out, int out_size, void* d_ws, size_t ws_size,
                              hipStream_t stream) {
    const float* a     = (const float*)d_in[0];
    const float* v     = (const float*)d_in[1];
    const float* gamma = (const float*)d_in[2];
    const float* beta  = (const float*)d_in[3];
    const float* W     = (const float*)d_in[4];
    const float* bias  = (const float*)d_in[5];
    float* out = (float*)d_out;

    float* cur = (float*)d_ws;
    float* mu     = cur; cur += 128;
    float* rsig   = cur; cur += 128;
    float* SgPart = cur; cur += NB * 2;                 // 2052
    float* SbPart = cur; cur += NB * 2;                 // 2052
    float* Pblk   = cur; cur += (size_t)NB * 2 * 128;   // 262656
    float* ahT    = cur; cur += (size_t)HP * 128;       // 65664
    float* vh512  = cur; cur += 128;
    float* gp     = cur; cur += (size_t)HP * GPS;       // 264708
    float* bp     = cur; cur += (size_t)HP * GPS;       // 264708
    unsigned short* vhT = (unsigned short*)cur;         // 128*512 ushorts

    prep_all<<<HP + 128 + 1 + 257, 256, 0, stream>>>(a, v, gamma, beta, gp, bp, vhT, vh512, ahT);
    stats_kernel<<<128, 256, 0, stream>>>(a, v, mu, rsig);
    stage1<<<NB, 512, 0, stream>>>(W, gp, bp, vhT, vh512, ahT, Pblk, SgPart, SbPart);
    finalize_kernel<<<OD, 128, 0, stream>>>(Pblk, SgPart, SbPart, mu, rsig, bias, out);
}

// Round 5
// 143.010 us; speedup vs baseline: 3.0801x; 1.6961x over previous
//
#include <hip/hip_runtime.h>

#define HID 512
#define OD  256
#define HP  513
#define NROWS 131328         /* 256*513 rows of Wg */
#define NBLK  1026           /* NROWS/128 */
#define KP    576            /* padded K (9*64) */
#define WRS   1152           /* Wg row stride in bytes (576 bf16) */
#define EPSV 1e-5f

typedef float f32x4 __attribute__((ext_vector_type(4)));
typedef short s16x8 __attribute__((ext_vector_type(8)));

#define GLDS16(g, l) __builtin_amdgcn_global_load_lds( \
    (const __attribute__((address_space(1))) void*)(g), \
    (__attribute__((address_space(3))) void*)(l), 16, 0, 0)

static __device__ __forceinline__ unsigned short f2bf(float f) {
    union { float f; unsigned u; } x; x.f = f;
    unsigned r = x.u + 0x7FFFu + ((x.u >> 16) & 1u);   // RNE
    return (unsigned short)(r >> 16);
}

// ---------- prep: vhT (bf16, swizzled, padded 576) + ahT --------------------
__global__ void prep_all(const float* __restrict__ a, const float* __restrict__ v,
                         unsigned short* __restrict__ vhT, float* __restrict__ ahT) {
    int b = blockIdx.x, t = threadIdx.x;
    if (b < 128) {
        int n = b;
        unsigned sw = (unsigned)((n & 7) << 4);
        for (int j = t; j < KP; j += 256) {
            float val = 0.f;
            if (j == 0) val = 1.f;
            else if (j <= 512) val = v[n * HID + j - 1];
            unsigned byte = (unsigned)n * WRS + (unsigned)((j >> 6) * 128)
                          + (((unsigned)((j & 63) * 2)) ^ sw);
            *(unsigned short*)((char*)vhT + byte) = f2bf(val);
        }
    } else {
        int idx = (b - 128) * 256 + t;
        if (idx < HP * 128) {
            int i = idx >> 7, m = idx & 127;
            ahT[idx] = (i == 0) ? 1.f : a[m * HID + i - 1];
        }
    }
}

// ---------- stats ------------------------------------------------------------
__global__ void stats_kernel(const float* __restrict__ a, const float* __restrict__ v,
                             float* __restrict__ mu, float* __restrict__ rsig) {
    __shared__ float s1[256], s2[256], s3[256], s4[256];
    int m = blockIdx.x, t = threadIdx.x;
    float a0 = a[m * HID + t], a1 = a[m * HID + t + 256];
    float v0 = v[m * HID + t], v1 = v[m * HID + t + 256];
    s1[t] = a0 + a1; s2[t] = a0 * a0 + a1 * a1;
    s3[t] = v0 + v1; s4[t] = v0 * v0 + v1 * v1;
    __syncthreads();
    for (int off = 128; off > 0; off >>= 1) {
        if (t < off) { s1[t] += s1[t + off]; s2[t] += s2[t + off];
                       s3[t] += s3[t + off]; s4[t] += s4[t + off]; }
        __syncthreads();
    }
    if (t == 0) {
        float Sa = 1.f + s1[0], Qa = 1.f + s2[0];
        float Sv = 1.f + s3[0], Qv = 1.f + s4[0];
        float muv = Sa * Sv / (float)(HP * HP);
        float var = Qa * Qv / (float)(HP * HP) - muv * muv;
        mu[m]   = muv;
        rsig[m] = rsqrtf(var + EPSV);
    }
}

// ---------- pass1: stream W, scale by gamma, pack bf16 swizzled --------------
// One wave per row. Coalesced dword loads; per-row sums (gamma*W, beta*W) -> rowS.
__global__ __launch_bounds__(256, 4) void scale_pack(
        const float* __restrict__ W, const float* __restrict__ gamma,
        const float* __restrict__ beta, unsigned short* __restrict__ Wg,
        float* __restrict__ rowS, int R0, int rows) {
    const int w = threadIdx.x >> 6, l = threadIdx.x & 63;
    const int row = R0 + blockIdx.x * 4 + w;
    const unsigned irow = (unsigned)row % 513u;
    const float* Wr = W + (size_t)row * 513u;
    const float* gr = gamma + (size_t)irow * 513u;
    const float* br = beta  + (size_t)irow * 513u;
    char* wrow = (char*)Wg + (size_t)(row - R0) * WRS;
    const unsigned sw = (unsigned)((row & 7) << 4);
    float sg = 0.f, sb = 0.f;
#pragma unroll
    for (int it = 0; it < 8; ++it) {
        int j = it * 64 + l;
        float wv = Wr[j], g = gr[j], bb = br[j];
        float p = g * wv;
        sg += p;
        sb = fmaf(bb, wv, sb);
        unsigned byte = (unsigned)(it * 128) + (((unsigned)(l * 2)) ^ sw);
        *(unsigned short*)(wrow + byte) = f2bf(p);
    }
    {   // tail chunk 8: j=512 (lane 0), zero pad cols 513..575
        float wv = 0.f, g = 0.f, bb = 0.f;
        if (l == 0) { wv = Wr[512]; g = gr[512]; bb = br[512]; }
        float p = g * wv;
        sg += p;
        sb = fmaf(bb, wv, sb);
        unsigned byte = 8u * 128u + (((unsigned)(l * 2)) ^ sw);
        *(unsigned short*)(wrow + byte) = f2bf(p);
    }
#pragma unroll
    for (int off = 1; off < 64; off <<= 1) {
        sg += __shfl_xor(sg, off);
        sb += __shfl_xor(sb, off);
    }
    if (l == 0) {
        float2 rs; rs.x = sg; rs.y = sb;
        *(float2*)(rowS + 2 * (size_t)row) = rs;
    }
}

// ---------- reduce rowS -> Sg[o], Sb[o] --------------------------------------
__global__ void sum_sgsb(const float* __restrict__ rowS,
                         float* __restrict__ Sg, float* __restrict__ Sb) {
    __shared__ float s1[256], s2[256];
    int o = blockIdx.x, t = threadIdx.x;
    float g = 0.f, bb = 0.f;
    for (int i = t; i < 513; i += 256) {
        float2 rs = *(const float2*)(rowS + 2 * (size_t)(o * 513 + i));
        g += rs.x; bb += rs.y;
    }
    s1[t] = g; s2[t] = bb;
    __syncthreads();
    for (int off = 128; off > 0; off >>= 1) {
        if (t < off) { s1[t] += s1[t + off]; s2[t] += s2[t + off]; }
        __syncthreads();
    }
    if (t == 0) { Sg[o] = s1[0]; Sb[o] = s2[0]; }
}

// ---------- pass2: bf16 GEMM via global_load_lds + swizzled ds_read_b128 -----
// A = Wg[128 rows x 576], B = vhT[128 x 576]; wave (wm,wn) owns 32M x 64N.
// Epilogue folds ah-weighted i-reduction, slot-split by o -> Pblk.
__global__ __launch_bounds__(512, 6) void gemm2(
        const unsigned short* __restrict__ Wg, const unsigned short* __restrict__ vhT,
        const float* __restrict__ ahT, float* __restrict__ Pblk, int R0) {
    __shared__ __align__(16) char As[16384];
    __shared__ __align__(16) char Bs[16384];
    __shared__ float red[2 * 128 * 4];

    const int tid = threadIdx.x, lane = tid & 63, w = tid >> 6;
    const int wm = w >> 1, wn = w & 1;
    const int lr = lane & 15, lg = lane >> 4;
    const int gr0 = R0 + blockIdx.x * 128;
    const int nb = gr0 >> 7;
    const unsigned ofirst = (unsigned)gr0 / 513u;
    const unsigned osw = (ofirst + 1u) * 513u;

    f32x4 acc[2][4];
#pragma unroll
    for (int mt = 0; mt < 2; ++mt)
#pragma unroll
        for (int nt = 0; nt < 4; ++nt) acc[mt][nt] = {0.f, 0.f, 0.f, 0.f};

    const size_t arow = (size_t)blockIdx.x * 128;
    for (int s = 0; s < 9; ++s) {
        // ---- stage A,B tiles (16 KB each): linear LDS dest, pre-swizzled src
#pragma unroll
        for (int c = 0; c < 2; ++c) {
            int u = c * 512 + tid;
            int r = u >> 3, off = (u & 7) * 16;
            GLDS16((const char*)Wg + (arow + r) * WRS + s * 128 + off, As + u * 16);
            GLDS16((const char*)vhT + (size_t)r * WRS + s * 128 + off, Bs + u * 16);
        }
        __syncthreads();   // compiler drains vmcnt before barrier -> tiles ready
        // ---- MFMA: 2 ks x (2 A-frags + 4 B-frags + 8 MFMA)
#pragma unroll
        for (int ks = 0; ks < 2; ++ks) {
            s16x8 afr[2], bfr[4];
#pragma unroll
            for (int mt = 0; mt < 2; ++mt) {
                unsigned r = (unsigned)(wm * 32 + mt * 16 + lr);
                unsigned cb = ((unsigned)(ks * 64 + lg * 16)) ^ ((r & 7u) << 4);
                afr[mt] = *(const s16x8*)(As + r * 128 + cb);
            }
#pragma unroll
            for (int nt = 0; nt < 4; ++nt) {
                unsigned n = (unsigned)(wn * 64 + nt * 16 + lr);
                unsigned cb = ((unsigned)(ks * 64 + lg * 16)) ^ ((n & 7u) << 4);
                bfr[nt] = *(const s16x8*)(Bs + n * 128 + cb);
            }
#pragma unroll
            for (int mt = 0; mt < 2; ++mt)
#pragma unroll
                for (int nt = 0; nt < 4; ++nt)
                    acc[mt][nt] = __builtin_amdgcn_mfma_f32_16x16x32_bf16(
                        afr[mt], bfr[nt], acc[mt][nt], 0, 0, 0);
        }
        __syncthreads();   // all waves done reading before next overwrite
    }

    // ---- epilogue: P[col] += ah[col,i] * T[oi][col], slot-split by o --------
    float p0[4], p1[4];
#pragma unroll
    for (int nt = 0; nt < 4; ++nt) { p0[nt] = 0.f; p1[nt] = 0.f; }
#pragma unroll
    for (int mt = 0; mt < 2; ++mt)
#pragma unroll
        for (int e = 0; e < 4; ++e) {
            unsigned oi = (unsigned)gr0 + (unsigned)(wm * 32 + mt * 16 + lg * 4 + e);
            bool hi = (oi >= osw);
            unsigned ii = oi - (hi ? osw : ofirst * 513u);
            const float* ahr = ahT + (size_t)ii * 128;
#pragma unroll
            for (int nt = 0; nt < 4; ++nt) {
                float val = acc[mt][nt][e] * ahr[wn * 64 + nt * 16 + lr];
                p0[nt] += hi ? 0.f : val;
                p1[nt] += hi ? val : 0.f;
            }
        }
#pragma unroll
    for (int nt = 0; nt < 4; ++nt) {
        float r0 = p0[nt], r1 = p1[nt];
        r0 += __shfl_xor(r0, 16); r0 += __shfl_xor(r0, 32);
        r1 += __shfl_xor(r1, 16); r1 += __shfl_xor(r1, 32);
        p0[nt] = r0; p1[nt] = r1;
    }
    if (lane < 16) {
#pragma unroll
        for (int nt = 0; nt < 4; ++nt) {
            int col = wn * 64 + nt * 16 + lr;
            red[(0 * 128 + col) * 4 + wm] = p0[nt];
            red[(1 * 128 + col) * 4 + wm] = p1[nt];
        }
    }
    __syncthreads();
    if (tid < 256) {
        int sl = tid >> 7, col = tid & 127;
        const float* rp = red + (size_t)(sl * 128 + col) * 4;
        float s = rp[0] + rp[1] + rp[2] + rp[3];
        Pblk[((size_t)nb * 2 + sl) * 128 + col] = s;
    }
}

// ---------- finalize ---------------------------------------------------------
__global__ void finalize_kernel(const float* __restrict__ Pblk, const float* __restrict__ Sg,
                                const float* __restrict__ Sb, const float* __restrict__ mu,
                                const float* __restrict__ rsig, const float* __restrict__ bias,
                                float* __restrict__ out) {
    int o = blockIdx.x, m = threadIdx.x;   // 128 threads
    int b0 = (o * HP) >> 7, b1 = (o * HP + 512) >> 7;
    float P = 0.f;
    for (int b = b0; b <= b1; ++b) {
        unsigned of = ((unsigned)b * 128u) / 513u;
        int sl = o - (int)of;
        if (sl >= 0 && sl <= 1) P += Pblk[((size_t)b * 2 + sl) * 128 + m];
    }
    float x = rsig[m] * (P - mu[m] * Sg[o]) + Sb[o] + bias[o];
    out[m * OD + o] = fmaxf(x, 0.f);
}

extern "C" void kernel_launch(void* const* d_in, const int* in_sizes, int n_in,
                              void* d_out, int out_size, void* d_ws, size_t ws_size,
                              hipStream_t stream) {
    const float* a     = (const float*)d_in[0];
    const float* v     = (const float*)d_in[1];
    const float* gamma = (const float*)d_in[2];
    const float* beta  = (const float*)d_in[3];
    const float* W     = (const float*)d_in[4];
    const float* bias  = (const float*)d_in[5];
    float* out = (float*)d_out;

    float* cur = (float*)d_ws;
    float* mu   = cur; cur += 128;
    float* rsig = cur; cur += 128;
    float* Sg   = cur; cur += 256;
    float* Sb   = cur; cur += 256;
    float* Pblk = cur; cur += (size_t)NBLK * 2 * 128;   // 262656
    float* ahT  = cur; cur += (size_t)HP * 128;         // 65664
    float* rowS = cur; cur += (size_t)NROWS * 2;        // 262656
    unsigned short* vhT = (unsigned short*)cur;          // 128*576 bf16
    cur += (size_t)128 * KP / 2;                         // 36864 floats
    unsigned short* Wring = (unsigned short*)cur;

    size_t fixedB = (size_t)((char*)Wring - (char*)d_ws);
    size_t avail  = (ws_size > fixedB) ? (ws_size - fixedB) : 0;
    int nch = 1;
    while (nch < 512) {
        size_t ring = (size_t)((NBLK + nch - 1) / nch) * 128 * WRS;
        if (ring <= avail) break;
        nch <<= 1;
    }
    int chblk = (NBLK + nch - 1) / nch;   // 128-row blocks per chunk

    prep_all<<<128 + 257, 256, 0, stream>>>(a, v, vhT, ahT);
    stats_kernel<<<128, 256, 0, stream>>>(a, v, mu, rsig);
    for (int c = 0; c < nch; ++c) {
        int bstart = c * chblk;
        int nb_c = NBLK - bstart; if (nb_c > chblk) nb_c = chblk;
        if (nb_c <= 0) break;
        int R0 = bstart * 128, rows = nb_c * 128;
        scale_pack<<<rows / 4, 256, 0, stream>>>(W, gamma, beta, Wring, rowS, R0, rows);
        gemm2<<<nb_c, 512, 0, stream>>>(Wring, vhT, ahT, Pblk, R0);
    }
    sum_sgsb<<<256, 256, 0, stream>>>(rowS, Sg, Sb);
    finalize_kernel<<<OD, 128, 0, stream>>>(Pblk, Sg, Sb, mu, rsig, bias, out);
}